// Round 10
// baseline (236.399 us; speedup 1.0000x reference)
//
#include <hip/hip_runtime.h>
#include <cstdint>

typedef unsigned long long u64;
typedef unsigned int u32;

#define B_ 4
#define N_ 3600
#define C_ 16
#define NW_ 57        // ceil(N/64) words of adjacency/valid bitmask
#define NPAD_ 3648    // NW_*64
#define RPW_ 4        // rows per wave (k_adj)
#define RPB_ 16       // rows per block (k_adj, 4 waves)
#define HW0_ 1856     // j-half 0: words 0..28  (29 words)
#define HW1_ 1792     // j-half 1: words 29..56 (28 words)
#define NBLK_ 15      // k_valid: blocks per image (15*256 = 3840 >= N)

// ---------------------------------------------------------------------------
// K1: adjacency bitmask (round-8 proven config). 4 rows/wave, 16 rows/block;
// j-range staged in LDS in two halves (29.7 KB -> 5 blocks/CU). Lane t holds
// row word t in a register -> one contiguous 456 B store per row.
//
// Exact division-free IoU test:
//   round_f32(inter/denom) >= 0.4f  <=>  inter > (0.4f - 2^-26)*denom in f64
//   (26x24-bit mantissa product is exact; midpoint ties round-to-even to
//   prev(0.4f) < 0.4f -> false, matching strict '>'). denom==0 => inter==0
//   => false, matching 0/0=NaN >= 0.4 false. Zero-padded boxes => false.
// ---------------------------------------------------------------------------
__global__ __launch_bounds__(256, 5) void k_adj(const float* __restrict__ boxes,
                                                u64* __restrict__ adj) {
#pragma clang fp contract(off)
    __shared__ float4 sbox[HW0_];    // (x1,y1,x2,y2), one j-half at a time
    const int tid  = threadIdx.x;
    const int lane = tid & 63;
    const int wv   = tid >> 6;
    const int g    = blockIdx.x;                 // 0 .. B*N/16-1
    const int b    = g / (N_ / RPB_);
    const int r0   = (g % (N_ / RPB_)) * RPB_ + wv * RPW_;
    const size_t bN = (size_t)b * N_;

    float4 bi[RPW_];
    float  ai[RPW_];
#pragma unroll
    for (int r = 0; r < RPW_; ++r) {
        const float4 bx = reinterpret_cast<const float4*>(boxes)[bN + r0 + r];
        const float x1 = bx.x - bx.z * 0.5f;   // cx - w/2 (reference op order)
        const float y1 = bx.y - bx.w * 0.5f;
        const float x2 = x1 + bx.z;
        const float y2 = y1 + bx.w;
        bi[r] = make_float4(x1, y1, x2, y2);
        ai[r] = (x2 - x1) * (y2 - y1);
    }
    const double MID = (double)0.4f - 0x1p-26;   // exact

    u64 row[RPW_];
#pragma unroll
    for (int r = 0; r < RPW_; ++r) row[r] = 0ull;

    int jbase = 0;
    for (int h = 0; h < 2; ++h) {
        const int cnt = h ? HW1_ : HW0_;
        __syncthreads();                         // protect previous half's reads
        for (int jj = tid; jj < cnt; jj += 256) {
            const int j = jbase + jj;
            float x1 = 0.f, y1 = 0.f, x2 = 0.f, y2 = 0.f;
            if (j < N_) {
                const float4 bx = reinterpret_cast<const float4*>(boxes)[bN + j];
                x1 = bx.x - bx.z * 0.5f;
                y1 = bx.y - bx.w * 0.5f;
                x2 = x1 + bx.z;
                y2 = y1 + bx.w;
            }
            sbox[jj] = make_float4(x1, y1, x2, y2);
        }
        __syncthreads();

        const int twn = cnt >> 6;
        for (int tw = 0; tw < twn; ++tw) {
            const int tglob = (jbase >> 6) + tw;
            const int j     = jbase + tw * 64 + lane;
            const float4 bj = sbox[tw * 64 + lane];
            const float ajr = (bj.z - bj.x) * (bj.w - bj.y);
#pragma unroll
            for (int r = 0; r < RPW_; ++r) {
                const float ltx = fmaxf(bi[r].x, bj.x);
                const float lty = fmaxf(bi[r].y, bj.y);
                const float rbx = fminf(bi[r].z, bj.z);
                const float rby = fminf(bi[r].w, bj.w);
                const float whx = fmaxf(rbx - ltx, 0.0f);
                const float why = fmaxf(rby - lty, 0.0f);
                const float inter = whx * why;
                const float denom = (ai[r] + ajr) - inter;
                const int pred = ((double)inter > MID * (double)denom) && (j != r0 + r);
                const u64 m = __ballot(pred);
                if (lane == tglob) row[r] = m;   // 2x v_cndmask
            }
        }
        jbase += cnt;
    }

#pragma unroll
    for (int r = 0; r < RPW_; ++r)
        if (lane < NW_) adj[(bN + r0 + r) * (size_t)NW_ + lane] = row[r];
}

// ---------------------------------------------------------------------------
// K1b: sparse threshold kernel. One wave per row: lane w iterates its adj
// word's set bits, gathers con[j][0..15], fmax-accumulates; 6-step shuffle
// max-reduce; thr[i][c] = max(adj_con, con_i). Exact: p>=a && p>=b <=>
// p >= fmax(a,b) for non-NaN; adj_con init 0 matches where(adj, con, 0).
// ---------------------------------------------------------------------------
__global__ __launch_bounds__(256) void k_acon(const u64* __restrict__ adj,
                                              const float* __restrict__ con,
                                              float* __restrict__ thr) {
    const int tid  = threadIdx.x;
    const int lane = tid & 63;
    const int wv   = tid >> 6;
    const int g    = blockIdx.x;                 // 0 .. B*N/4-1
    const int b    = g / (N_ / 4);
    const int i    = (g % (N_ / 4)) * 4 + wv;
    const size_t bN = (size_t)b * N_;

    u64 w = (lane < NW_) ? adj[(bN + i) * (size_t)NW_ + lane] : 0ull;

    float cm[C_];
#pragma unroll
    for (int k = 0; k < C_; ++k) cm[k] = 0.0f;

    while (w) {
        const int bit = __builtin_ctzll(w); w &= w - 1;
        const int j   = lane * 64 + bit;
        const float4* cp = reinterpret_cast<const float4*>(con + (bN + j) * C_);
        const float4 c0 = cp[0], c1 = cp[1], c2 = cp[2], c3 = cp[3];
        cm[0]  = fmaxf(cm[0],  c0.x); cm[1]  = fmaxf(cm[1],  c0.y);
        cm[2]  = fmaxf(cm[2],  c0.z); cm[3]  = fmaxf(cm[3],  c0.w);
        cm[4]  = fmaxf(cm[4],  c1.x); cm[5]  = fmaxf(cm[5],  c1.y);
        cm[6]  = fmaxf(cm[6],  c1.z); cm[7]  = fmaxf(cm[7],  c1.w);
        cm[8]  = fmaxf(cm[8],  c2.x); cm[9]  = fmaxf(cm[9],  c2.y);
        cm[10] = fmaxf(cm[10], c2.z); cm[11] = fmaxf(cm[11], c2.w);
        cm[12] = fmaxf(cm[12], c3.x); cm[13] = fmaxf(cm[13], c3.y);
        cm[14] = fmaxf(cm[14], c3.z); cm[15] = fmaxf(cm[15], c3.w);
    }

#pragma unroll
    for (int off = 1; off < 64; off <<= 1) {
#pragma unroll
        for (int k = 0; k < C_; ++k) cm[k] = fmaxf(cm[k], __shfl_xor(cm[k], off));
    }
    if (lane == 0) {
        const float4* cp = reinterpret_cast<const float4*>(con + (bN + i) * C_);
        const float4 c0 = cp[0], c1 = cp[1], c2 = cp[2], c3 = cp[3];
        float4* o = reinterpret_cast<float4*>(thr + (bN + i) * C_);
        o[0] = make_float4(fmaxf(cm[0],  c0.x), fmaxf(cm[1],  c0.y),
                           fmaxf(cm[2],  c0.z), fmaxf(cm[3],  c0.w));
        o[1] = make_float4(fmaxf(cm[4],  c1.x), fmaxf(cm[5],  c1.y),
                           fmaxf(cm[6],  c1.z), fmaxf(cm[7],  c1.w));
        o[2] = make_float4(fmaxf(cm[8],  c2.x), fmaxf(cm[9],  c2.y),
                           fmaxf(cm[10], c2.z), fmaxf(cm[11], c2.w));
        o[3] = make_float4(fmaxf(cm[12], c3.x), fmaxf(cm[13], c3.y),
                           fmaxf(cm[14], c3.z), fmaxf(cm[15], c3.w));
    }
}

// ---------------------------------------------------------------------------
// K2: coalesced valid0 + global compaction. One thread per box, all 16 c.
// Nondeterministic compaction order is erased by k_main's sort.
// ---------------------------------------------------------------------------
__global__ __launch_bounds__(256) void k_valid(const float* __restrict__ pro,
                                               const float* __restrict__ thr,
                                               const float* __restrict__ conf,
                                               u64* __restrict__ keys_ws,
                                               u64* __restrict__ pvm_ws,
                                               u32* __restrict__ tcnt) {
    const int lane = threadIdx.x & 63;
    const int wv   = threadIdx.x >> 6;
    const int b    = blockIdx.x / NBLK_;
    const int blk  = blockIdx.x % NBLK_;
    const int i    = blk * 256 + wv * 64 + lane;
    const size_t bN = (size_t)b * N_;
    const int inb  = (i < N_);
    const int word = blk * 4 + wv;               // 0..59; words >=57 unused

    float pv[C_], tv[C_];
    if (inb) {
        const float4* pp = reinterpret_cast<const float4*>(pro + (bN + i) * C_);
        const float4* tp = reinterpret_cast<const float4*>(thr + (bN + i) * C_);
#pragma unroll
        for (int k = 0; k < 4; ++k) {
            const float4 a = pp[k];
            pv[4*k] = a.x; pv[4*k+1] = a.y; pv[4*k+2] = a.z; pv[4*k+3] = a.w;
            const float4 t = tp[k];
            tv[4*k] = t.x; tv[4*k+1] = t.y; tv[4*k+2] = t.z; tv[4*k+3] = t.w;
        }
    } else {
#pragma unroll
        for (int k = 0; k < C_; ++k) { pv[k] = 0.f; tv[k] = 0.f; }
    }

#pragma unroll
    for (int c = 0; c < C_; ++c) {
        const float cf = conf[c];
        const int pred = inb && (pv[c] >= cf) && (pv[c] >= tv[c]);
        const u64 bm = __ballot(pred);
        const size_t bc = (size_t)b * C_ + c;
        if (lane == 0) pvm_ws[bc * 64 + word] = bm;
        u32 base = 0;
        if (lane == 0 && bm) base = atomicAdd(&tcnt[bc], (u32)__popcll(bm));
        base = (u32)__shfl((int)base, 0);
        if (pred) {
            const u32 pb_ = __float_as_uint(pv[c]);
            const u32 pk  = pb_ ^ ((pb_ >> 31) ? 0xFFFFFFFFu : 0x80000000u);
            keys_ws[bc * N_ + base + (u32)__popcll(bm & ((1ull << lane) - 1ull))]
                = (((u64)(~pk)) << 32) | (u32)i;
        }
    }
}

// ---------------------------------------------------------------------------
// K3: sort + gather-compacted chunked greedy + output. One block per (b,c).
// vmask (valid bitmask) lives in LDS. Pipeline per chunk (2 barriers):
//   phase 1: wave0 resolves chunk ch (ext-check -> sparse resolve ->
//            batched-8 apply into vmask); wave1 GATHERS the next 64
//            currently-valid candidates for chunk ch+2 (cursor scan; benign
//            1->0 race with wave0's clears => superset, re-checked at
//            resolve); waves 2-3 stage rows for chunk ch+1.
//   phase 2: all waves build sintra for chunk ch+1 (symmetry ballots).
// Exactness: skipping invalid candidates at gather is exact (validity only
// shrinks; accepted => valid at all earlier times => gathered). Order is
// preserved (cursor scan). Accept rule identical to rounds 7-9. Survivors in
// greedy order == reference output order (suppressed rows exact zeros).
// ---------------------------------------------------------------------------
__global__ __launch_bounds__(256, 1) void k_main(const u64* __restrict__ keys_ws,
                                                 const u64* __restrict__ pvm_ws,
                                                 const u32* __restrict__ tcnt,
                                                 const u64* __restrict__ adj,
                                                 const float* __restrict__ pro,
                                                 const float* __restrict__ boxes,
                                                 const float* __restrict__ scales,
                                                 float* __restrict__ out) {
#pragma clang fp contract(off)
    __shared__ u64 keys[4096];
    __shared__ u32 sidx[NPAD_];
    __shared__ u32 slist[NPAD_];
    __shared__ u64 buf[2][64 * NW_];
    __shared__ u64 sintra[2][64];
    __shared__ u64 vmask[NW_];
    __shared__ u32 clist[3][64];
    __shared__ u32 ccount[3];
    __shared__ u32 s_cursor;
    __shared__ u32 sacc[64];
    __shared__ u32 s_S;

    const int tid  = threadIdx.x;
    const int lane = tid & 63;
    const int wv   = tid >> 6;
    const int bc   = blockIdx.x;
    const int b    = bc / C_, c = bc % C_;
    const size_t bN = (size_t)b * N_;

    const int T = (int)tcnt[bc];

    // --- load + sort keys (asc => score desc, idx asc) ---
    for (int x = tid; x < T; x += 256) keys[x] = keys_ws[(size_t)bc * N_ + x];
    int P = 2;
    while (P < T) P <<= 1;                       // P <= 4096
    for (int x = T + tid; x < P; x += 256) keys[x] = ~0ull;
    if (tid < NW_) vmask[tid] = pvm_ws[(size_t)bc * 64 + tid];
    __syncthreads();
    for (int k = 2; k <= P; k <<= 1) {
        for (int j = k >> 1; j > 0; j >>= 1) {
            for (int t = tid; t < P; t += 256) {
                const int ixj = t ^ j;
                if (ixj > t) {
                    const u64 a = keys[t], bb = keys[ixj];
                    const bool up = ((t & k) == 0);
                    if ((a > bb) == up) { keys[t] = bb; keys[ixj] = a; }
                }
            }
            __syncthreads();
        }
    }
    for (int x = tid; x < T; x += 256) sidx[x] = (u32)(keys[x] & 0xFFFFFFFFull);

    // --- prologue: chunks 0,1 = first 128 sorted candidates (all valid) ---
    const int cn0 = (T < 64) ? T : 64;
    const int cn1 = (T > 64) ? ((T - 64 < 64) ? T - 64 : 64) : 0;
    if (tid < 64)       clist[0][tid] = (tid < cn0) ? 0u : 0u;  // placeholder
    if (tid == 0) { ccount[0] = (u32)cn0; ccount[1] = (u32)cn1;
                    s_cursor = (u32)((T < 128) ? T : 128); s_S = 0; }
    __syncthreads();
    if (tid < 64)  clist[0][tid] = (tid < cn0) ? sidx[tid] : 0u;
    else if (tid < 128) { const int r = tid - 64;
                          clist[1][r] = (r < cn1) ? sidx[64 + r] : 0u; }
    __syncthreads();
    // stage buf[0]
#pragma unroll
    for (int rr = 0; rr < 16; ++rr) {
        const int r = wv * 16 + rr;
        const u32 idx = (r < cn0) ? clist[0][r] : 0u;
        if (lane < NW_)
            buf[0][(size_t)r * NW_ + lane] = adj[(bN + idx) * (size_t)NW_ + lane];
    }
    __syncthreads();
    // build sintra[0]
#pragma unroll
    for (int rr = 0; rr < 16; ++rr) {
        const int r = wv * 16 + rr;
        const u32 idxr = (r < cn0) ? clist[0][r] : 0u;
        const u64 rj = buf[0][(size_t)lane * NW_ + (idxr >> 6)];
        const u64 ib = __ballot((lane < cn0) && ((rj >> (idxr & 63)) & 1ull));
        if (lane == 0) sintra[0][r] = (r < cn0) ? ib : 0ull;
    }
    __syncthreads();

    // --- chunk loop ---
    for (int ch = 0; ; ++ch) {
        const int cg = ch % 3;
        const int pb = ch & 1;
        const int cn = (int)ccount[cg];
        if (cn == 0) break;

        // ---------- phase 1 ----------
        if (wv == 0) {
            // resolve chunk ch
            const u32 idxme = (lane < cn) ? clist[cg][lane] : 0u;
            const u64 vm = vmask[idxme >> 6];
            u64 cv = __ballot((lane < cn) && ((vm >> (idxme & 63)) & 1ull));
            const u64 iv = sintra[pb][lane];
            const u32 ivLo = (u32)iv, ivHi = (u32)(iv >> 32);
            u64 accept = 0ull;
            int na = 0;
            while (cv) {
                const int r = (int)__builtin_ctzll(cv);
                accept |= 1ull << r;
                if (lane == 0) sacc[na] = (u32)r;
                ++na;
                const u64 ir =
                    ((u64)(u32)__builtin_amdgcn_readlane((int)ivHi, r) << 32)
                  |  (u64)(u32)__builtin_amdgcn_readlane((int)ivLo, r);
                cv &= ~(ir | (1ull << r));
            }
            // emit survivors in greedy order
            u32 S = s_S;
            if ((accept >> lane) & 1ull) {
                const u32 pos = S + (u32)__popcll(accept & ((1ull << lane) - 1ull));
                slist[pos] = idxme;
            }
            if (lane == 0) s_S = S + (u32)__popcll(accept);
            // batched-8 apply into vmask
            const int l57 = (lane < NW_) ? lane : NW_ - 1;
            u64 acc = 0ull;
            for (int q0 = 0; q0 < na; q0 += 8) {
                const u32 r0 = sacc[q0];
                const u32 r1 = (q0 + 1 < na) ? sacc[q0 + 1] : r0;
                const u32 r2 = (q0 + 2 < na) ? sacc[q0 + 2] : r0;
                const u32 r3 = (q0 + 3 < na) ? sacc[q0 + 3] : r0;
                const u32 r4 = (q0 + 4 < na) ? sacc[q0 + 4] : r0;
                const u32 r5 = (q0 + 5 < na) ? sacc[q0 + 5] : r0;
                const u32 r6 = (q0 + 6 < na) ? sacc[q0 + 6] : r0;
                const u32 r7 = (q0 + 7 < na) ? sacc[q0 + 7] : r0;
                const u64 a0 = buf[pb][(size_t)r0 * NW_ + l57];
                const u64 a1 = buf[pb][(size_t)r1 * NW_ + l57];
                const u64 a2 = buf[pb][(size_t)r2 * NW_ + l57];
                const u64 a3 = buf[pb][(size_t)r3 * NW_ + l57];
                const u64 a4 = buf[pb][(size_t)r4 * NW_ + l57];
                const u64 a5 = buf[pb][(size_t)r5 * NW_ + l57];
                const u64 a6 = buf[pb][(size_t)r6 * NW_ + l57];
                const u64 a7 = buf[pb][(size_t)r7 * NW_ + l57];
                acc |= (a0 | a1) | (a2 | a3) | ((a4 | a5) | (a6 | a7));
            }
            if (lane < NW_ && acc) vmask[lane] &= ~acc;   // sole writer
        } else if (wv == 1) {
            // gather chunk ch+2 (superset under benign 1->0 race)
            const int tg = (ch + 2) % 3;
            u32 cnt = 0;
            u32 cur = s_cursor;
            while (cnt < 64u && cur < (u32)T) {
                const int pos = (int)cur + lane;
                const u32 idx = (pos < T) ? sidx[pos] : 0u;
                int v = 0;
                if (pos < T) {
                    const u64 w = vmask[idx >> 6];
                    v = (int)((w >> (idx & 63)) & 1ull);
                }
                const u64 bm = __ballot(v);
                const u32 nb = (u32)__popcll(bm);
                const u32 room = 64u - cnt;
                const u32 take = (nb < room) ? nb : room;
                if (v) {
                    const u32 rk = (u32)__popcll(bm & ((1ull << lane) - 1ull));
                    if (rk < take) clist[tg][cnt + rk] = idx;
                }
                const u32 span = ((u32)T - cur < 64u) ? ((u32)T - cur) : 64u;
                if (take == nb) cur += span;
                else {
                    u64 mm = bm;
                    for (u32 s = 0; s < take; ++s) mm &= mm - 1;
                    cur += (u32)__builtin_ctzll(mm);
                }
                cnt += take;
            }
            if (lane == 0) { ccount[tg] = cnt; s_cursor = cur; }
        } else {
            // stage rows for chunk ch+1
            const int ng = (ch + 1) % 3;
            const int cnn = (int)ccount[ng];
#pragma unroll
            for (int k = 0; k < 32; ++k) {
                const int r = (wv - 2) * 32 + k;
                const u32 idx = (r < cnn) ? clist[ng][r] : 0u;
                if (lane < NW_)
                    buf[pb ^ 1][(size_t)r * NW_ + lane] =
                        adj[(bN + idx) * (size_t)NW_ + lane];
            }
        }
        __syncthreads();

        // ---------- phase 2: build sintra for chunk ch+1 ----------
        {
            const int ng = (ch + 1) % 3;
            const int cnn = (int)ccount[ng];
#pragma unroll
            for (int rr = 0; rr < 16; ++rr) {
                const int r = wv * 16 + rr;
                const u32 idxr = (r < cnn) ? clist[ng][r] : 0u;
                const u64 rj = buf[pb ^ 1][(size_t)lane * NW_ + (idxr >> 6)];
                const u64 ib = __ballot((lane < cnn) && ((rj >> (idxr & 63)) & 1ull));
                if (lane == 0) sintra[pb ^ 1][r] = (r < cnn) ? ib : 0ull;
            }
        }
        __syncthreads();
    }

    // --- output survivors in greedy order (suppressed rows stay zeros) ---
    const int Sf = (int)s_S;
    const float s = scales[b];
    for (int r = tid; r < Sf; r += 256) {
        const int idx = (int)slist[r];
        const float4 bx = reinterpret_cast<const float4*>(boxes)[bN + idx];
        const float scx = bx.x * s, scy = bx.y * s, sw = bx.z * s, sh = bx.w * s;
        float* o = out + ((size_t)bc * N_ + r) * 5;
        o[0] = scx - 0.5f * sw;
        o[1] = scy - 0.5f * sh;
        o[2] = scx + 0.5f * sw;
        o[3] = scy + 0.5f * sh;
        o[4] = pro[(bN + idx) * C_ + c];
        out[(size_t)B_ * C_ * N_ * 5 + (size_t)bc * N_ + r] = 1.0f;
    }
}

// ---------------------------------------------------------------------------
extern "C" void kernel_launch(void* const* d_in, const int* in_sizes, int n_in,
                              void* d_out, int out_size, void* d_ws, size_t ws_size,
                              hipStream_t stream) {
    const float* pro    = (const float*)d_in[0];   // (B,N,C)
    const float* con    = (const float*)d_in[1];   // (B,N,C)
    const float* boxes  = (const float*)d_in[2];   // (B,N,4)
    const float* scales = (const float*)d_in[3];   // (B,)
    const float* conf   = (const float*)d_in[4];   // (C,)

    char* ws = (char*)d_ws;
    u64* adj = (u64*)ws;                                   // B*N*NW u64  (6.57 MB)
    size_t off = (size_t)B_ * N_ * NW_ * sizeof(u64);
    float* thr = (float*)(ws + off);                       // B*N*C f32   (0.92 MB)
    off += (size_t)B_ * N_ * C_ * sizeof(float);
    u64* keys_ws = (u64*)(ws + off);                       // B*C*N u64   (1.84 MB)
    off += (size_t)B_ * C_ * N_ * sizeof(u64);
    u64* pvm_ws = (u64*)(ws + off);                        // 64*64 u64   (32 KB)
    off += (size_t)B_ * C_ * 64 * sizeof(u64);
    u32* tcnt = (u32*)(ws + off);                          // 64 u32

    hipMemsetAsync(d_out, 0, (size_t)out_size * sizeof(float), stream);
    hipMemsetAsync(tcnt, 0, B_ * C_ * sizeof(u32), stream);
    k_adj  <<<B_ * N_ / RPB_, 256, 0, stream>>>(boxes, adj);
    k_acon <<<B_ * N_ / 4,    256, 0, stream>>>(adj, con, thr);
    k_valid<<<B_ * NBLK_,     256, 0, stream>>>(pro, thr, conf, keys_ws, pvm_ws, tcnt);
    k_main <<<B_ * C_,        256, 0, stream>>>(keys_ws, pvm_ws, tcnt, adj, pro,
                                                boxes, scales, (float*)d_out);
}